// Round 5
// baseline (244.572 us; speedup 1.0000x reference)
//
#include <hip/hip_runtime.h>
#include <hip/hip_bf16.h>
#include <math.h>

#define BB 1024     // batch
#define LL 50       // sequence length
#define DD 256      // embedding dim
#define TWO_D 512
#define NN 40000    // nodes
#define DEG 12      // neighbors per node (adj_rows = repeat(arange(N), DEG))
#define NITER 50    // entmax bisect iterations

typedef __attribute__((ext_vector_type(8))) short short8;
typedef __attribute__((ext_vector_type(4))) float floatx4;

__device__ __forceinline__ float wave_sum64(float v) {
#pragma unroll
    for (int off = 32; off > 0; off >>= 1) v += __shfl_xor(v, off, 64);
    return v;
}
__device__ __forceinline__ float wave_max64(float v) {
#pragma unroll
    for (int off = 32; off > 0; off >>= 1) v = fmaxf(v, __shfl_xor(v, off, 64));
    return v;
}
__device__ __forceinline__ float bf2f(ushort u) {
    union { unsigned int i; float f; } c; c.i = ((unsigned int)u) << 16; return c.f;
}
__device__ __forceinline__ ushort f2bf(float f) {
    __hip_bfloat16 h = __float2bfloat16(f);
    return *(ushort*)&h;
}
// hardware transcendentals: v_exp_f32 (2^x), v_log_f32 (log2 x)
__device__ __forceinline__ float hw_exp2(float x) { return __builtin_amdgcn_exp2f(x); }
__device__ __forceinline__ float hw_log2(float x) { return __builtin_amdgcn_logf(x); }

// K0: ebf = bf16(item_emb)
__global__ __launch_bounds__(256) void k_emb_bf16(
    const float* __restrict__ emb, ushort* __restrict__ ebf)
{
    int i = (blockIdx.x * 256 + threadIdx.x) * 4;
    float4 v = *(const float4*)(emb + i);
    ushort4 o;
    o.x = f2bf(v.x); o.y = f2bf(v.y); o.z = f2bf(v.z); o.w = f2bf(v.w);
    *(ushort4*)(ebf + i) = o;
}

// K1: per-node conv from bf16 table. One wave per node, 4 nodes/block.
// gbf[n,d] = bf16( 0.5*(ebf[n,d] + sum_k val*ebf[col,d]) )
__global__ __launch_bounds__(256) void k_conv_all_bf16(
    const ushort* __restrict__ ebf, const int* __restrict__ adj_cols,
    const float* __restrict__ adj_vals, ushort* __restrict__ gbf)
{
    int wv = threadIdx.x >> 6, lane = threadIdx.x & 63;
    int n = blockIdx.x * 4 + wv;
    int colv = 0; float valv = 0.f;
    if (lane < DEG) { colv = adj_cols[n * DEG + lane]; valv = adj_vals[n * DEG + lane]; }
    ushort4 s = *(const ushort4*)(ebf + (size_t)n * DD + lane * 4);
    float a0 = bf2f(s.x), a1 = bf2f(s.y), a2 = bf2f(s.z), a3 = bf2f(s.w);
#pragma unroll
    for (int k = 0; k < DEG; ++k) {
        int   c = __shfl(colv, k, 64);
        float v = __shfl(valv, k, 64);
        ushort4 e = *(const ushort4*)(ebf + (size_t)c * DD + lane * 4);
        a0 += v * bf2f(e.x); a1 += v * bf2f(e.y);
        a2 += v * bf2f(e.z); a3 += v * bf2f(e.w);
    }
    ushort4 o;
    o.x = f2bf(0.5f * a0); o.y = f2bf(0.5f * a1);
    o.z = f2bf(0.5f * a2); o.w = f2bf(0.5f * a3);
    *(ushort4*)(gbf + (size_t)n * DD + lane * 4) = o;
}

// Kprep: w1t[n*256+k] = bf16(at_w1[k*256+n])
__global__ __launch_bounds__(256) void k_prep_w1(
    const float* __restrict__ at_w1, ushort* __restrict__ w1t)
{
    __shared__ ushort s[4][DD];
    int k0 = blockIdx.x * 4;
    int n = threadIdx.x;
#pragma unroll
    for (int j = 0; j < 4; ++j) s[j][n] = f2bf(at_w1[(k0 + j) * DD + n]);
    __syncthreads();
    ushort4 pk;
    pk.x = s[0][n]; pk.y = s[1][n]; pk.z = s[2][n]; pk.w = s[3][n];
    *(ushort4*)(w1t + n * DD + k0) = pk;
}

// K2 (fused target/t2/alpha): per block 4 batch rows.
//  te = tgt@wf_w^T + wf_b (kept in LDS only)
//  t2 = te@at_w2 + at_bias  -> global
//  alpha = sigmoid(te . aw + ab)+1 -> global
__global__ __launch_bounds__(256) void k_tprep(
    const float* __restrict__ tgt, const float* __restrict__ wf_w,
    const float* __restrict__ wf_b, const float* __restrict__ at_w2,
    const float* __restrict__ at_bias, const float* __restrict__ aw,
    const float* __restrict__ ab, float* __restrict__ t2,
    float* __restrict__ alpha)
{
    __shared__ float x_s[4 * TWO_D];
    __shared__ float te_s[4][DD];
    int b0 = blockIdx.x * 4;
    int tid = threadIdx.x;
    int wv = tid >> 6, lane = tid & 63;
    for (int i = tid; i < 4 * TWO_D; i += 256) x_s[i] = tgt[b0 * TWO_D + i];
    __syncthreads();

    float bias = wf_b[tid];
    float acc[4] = {bias, bias, bias, bias};
    const float4* w4 = (const float4*)(wf_w + tid * TWO_D);
    for (int kk = 0; kk < TWO_D / 4; ++kk) {
        float4 w = w4[kk];
#pragma unroll
        for (int j = 0; j < 4; ++j) {
            const float* xs = x_s + j * TWO_D + kk * 4;
            acc[j] += xs[0] * w.x + xs[1] * w.y + xs[2] * w.z + xs[3] * w.w;
        }
    }
#pragma unroll
    for (int j = 0; j < 4; ++j) te_s[j][tid] = acc[j];
    __syncthreads();

    float bias2 = at_bias[tid];
    float acc2[4] = {bias2, bias2, bias2, bias2};
    for (int k = 0; k < DD; ++k) {
        float w = at_w2[k * DD + tid];
#pragma unroll
        for (int j = 0; j < 4; ++j) acc2[j] += te_s[j][k] * w;
    }
#pragma unroll
    for (int j = 0; j < 4; ++j) t2[(b0 + j) * DD + tid] = acc2[j];

    // alpha: wave wv handles batch b0+wv
    float s = te_s[wv][lane] * aw[lane] + te_s[wv][lane + 64] * aw[lane + 64]
            + te_s[wv][lane + 128] * aw[lane + 128] + te_s[wv][lane + 192] * aw[lane + 192];
    s = wave_sum64(s);
    if (lane == 0) {
        float x = s + ab[0];
        float a = 1.f + 1.f / (1.f + expf(-x));
        if (a == 1.f) a = 1.00001f;
        alpha[b0 + wv] = a;
    }
}

// K3 (MFMA): G = gbf @ W1   (node-level, sequential A, coalesced bf16 output)
// grid 625, block 256 (4 waves). Tile 64 rows x 256 cols, K in 4 chunks of 64.
__global__ __launch_bounds__(256) void k_gw1(
    const ushort* __restrict__ gbf, const ushort* __restrict__ w1t,
    ushort* __restrict__ G)
{
    __shared__ __align__(16) ushort sA[64 * 72];    //  9216 B
    __shared__ __align__(16) ushort sB[256 * 72];   // 36864 B (reused for epilogue)
    int tid = threadIdx.x;
    int blk = blockIdx.x;
    int lane = tid & 63, wv = tid >> 6;
    int cn = lane & 15, q = lane >> 4;
    int n0 = wv * 64;
    const size_t rowbase = (size_t)blk * 64;

    floatx4 acc[4][4];
#pragma unroll
    for (int mt = 0; mt < 4; ++mt)
#pragma unroll
        for (int nt = 0; nt < 4; ++nt)
            acc[mt][nt] = (floatx4){0.f, 0.f, 0.f, 0.f};

#pragma unroll 1
    for (int kc = 0; kc < 4; ++kc) {
#pragma unroll
        for (int it = 0; it < 2; ++it) {
            int i = tid + it * 256;
            int row = i >> 3, seg = i & 7;
            *(uint4*)(sA + row * 72 + seg * 8) =
                *(const uint4*)(gbf + (rowbase + row) * DD + kc * 64 + seg * 8);
        }
#pragma unroll
        for (int it = 0; it < 8; ++it) {
            int i = tid + it * 256;
            int n = i >> 3, seg = i & 7;
            *(uint4*)(sB + n * 72 + seg * 8) =
                *(const uint4*)(w1t + n * DD + kc * 64 + seg * 8);
        }
        __syncthreads();
#pragma unroll
        for (int ks = 0; ks < 2; ++ks) {
            short8 af[4], bfr[4];
#pragma unroll
            for (int mt = 0; mt < 4; ++mt)
                af[mt] = *(const short8*)(sA + (mt * 16 + cn) * 72 + ks * 32 + q * 8);
#pragma unroll
            for (int nt = 0; nt < 4; ++nt)
                bfr[nt] = *(const short8*)(sB + (n0 + nt * 16 + cn) * 72 + ks * 32 + q * 8);
#pragma unroll
            for (int mt = 0; mt < 4; ++mt)
#pragma unroll
                for (int nt = 0; nt < 4; ++nt)
                    acc[mt][nt] = __builtin_amdgcn_mfma_f32_16x16x32_bf16(
                        af[mt], bfr[nt], acc[mt][nt], 0, 0, 0);
        }
        __syncthreads();
    }

    // epilogue: bf16 via LDS for coalesced stores
    ushort (*oS)[DD] = (ushort(*)[DD])sB;
#pragma unroll
    for (int mt = 0; mt < 4; ++mt)
#pragma unroll
        for (int nt = 0; nt < 4; ++nt)
#pragma unroll
            for (int r = 0; r < 4; ++r)
                oS[mt * 16 + q * 4 + r][n0 + nt * 16 + cn] = f2bf(acc[mt][nt][r]);
    __syncthreads();
#pragma unroll
    for (int it = 0; it < 8; ++it) {
        int i = tid + it * 256;
        int row = i >> 5, seg = i & 31;
        *(uint4*)(G + (rowbase + row) * DD + seg * 8) = *(const uint4*)(&oS[row][seg * 8]);
    }
}

__device__ __forceinline__ float pw(float z, float invv) {
    // z^invv for z>=0, invv>0.  log2(0)=-inf -> exp2(-inf)=0, correct limit.
    return hw_exp2(invv * hw_log2(z));
}

// K4 (fused): per batch b:
//   scores[l] = sum_d relu(G[item_l,d]+t2[b,d])*w0[d]   (gathered, in-register)
//   entmax-bisect over L (wave 0)
//   c[d] = sum_l attn[l]*gbf[item_l,d];  selu; L2-normalize -> out
__global__ __launch_bounds__(256) void k_fused_entmax(
    const int* __restrict__ items, const ushort* __restrict__ G,
    const ushort* __restrict__ gbf, const float* __restrict__ t2,
    const float* __restrict__ alpha, const float* __restrict__ at_w0,
    float* __restrict__ out)
{
    __shared__ int s_it[LL];
    __shared__ float sred[LL][4];
    __shared__ float attn_s[LL];
    __shared__ float red[4];
    int b = blockIdx.x;
    int tid = threadIdx.x;
    int lane = tid & 63, wv = tid >> 6;

    if (tid < LL) s_it[tid] = items[b * LL + tid];
    __syncthreads();

    // phase 1: scores
    float t2v = t2[b * DD + tid];
    float w0v = at_w0[tid];
#pragma unroll
    for (int l = 0; l < LL; ++l) {
        float g = bf2f(G[(size_t)s_it[l] * DD + tid]);
        float p = fmaxf(g + t2v, 0.f) * w0v;
        p = wave_sum64(p);
        if (lane == 0) sred[l][wv] = p;
    }
    __syncthreads();

    // phase 2: entmax bisect on wave 0 (score per lane, in register)
    if (tid < 64) {
        int l = tid;
        float x = (l < LL) ? (sred[l][0] + sred[l][1] + sred[l][2] + sred[l][3])
                           : -__builtin_inff();
        float a = alpha[b];
        float am1 = a - 1.f;
        float invv = 1.f / am1;
        float Xa = x * am1;

        float mx = wave_max64(Xa);
        float tau_lo = mx - 1.f;
        float tau_hi = mx - hw_exp2(am1 * hw_log2(1.f / (float)LL));

        float f_lo = wave_sum64(pw(fmaxf(Xa - tau_lo, 0.f), invv)) - 1.f;

        float dm = tau_hi - tau_lo;
        float tau_m = tau_lo;
#pragma unroll 1
        for (int it = 0; it < NITER; ++it) {
            dm *= 0.5f;
            tau_m = tau_lo + dm;
            float f_m = wave_sum64(pw(fmaxf(Xa - tau_m, 0.f), invv)) - 1.f;
            if (f_m * f_lo >= 0.f) tau_lo = tau_m;
        }
        float pm = pw(fmaxf(Xa - tau_m, 0.f), invv);
        float s = wave_sum64(pm);
        if (l < LL) attn_s[l] = pm / s;
    }
    __syncthreads();

    // phase 3: weighted sum + selu + L2 norm
    float c = 0.f;
#pragma unroll
    for (int l = 0; l < LL; ++l)
        c += attn_s[l] * bf2f(gbf[(size_t)s_it[l] * DD + tid]);

    const float SC = 1.0507009873554805f;
    const float AL = 1.6732632423543772f;
    c = SC * (c > 0.f ? c : AL * expm1f(c));

    float ss = wave_sum64(c * c);
    if (lane == 0) red[wv] = ss;
    __syncthreads();
    float tot = red[0] + red[1] + red[2] + red[3];
    out[b * DD + tid] = c / sqrtf(tot);
}

extern "C" void kernel_launch(void* const* d_in, const int* in_sizes, int n_in,
                              void* d_out, int out_size, void* d_ws, size_t ws_size,
                              hipStream_t stream) {
    const int*   items     = (const int*)  d_in[0];
    const float* tgt       = (const float*)d_in[3];
    const float* item_emb  = (const float*)d_in[4];
    const int*   adj_cols  = (const int*)  d_in[6];
    const float* adj_vals  = (const float*)d_in[7];
    const float* wf_w      = (const float*)d_in[8];
    const float* wf_b      = (const float*)d_in[9];
    const float* alphaw_w  = (const float*)d_in[10];
    const float* alphaw_b  = (const float*)d_in[11];
    const float* at_w0     = (const float*)d_in[12];
    const float* at_w1     = (const float*)d_in[13];
    const float* at_w2     = (const float*)d_in[14];
    const float* at_bias   = (const float*)d_in[15];

    const size_t SZ_TAB = (size_t)NN * DD * sizeof(ushort);      // 20.48 MB
    char* ws = (char*)d_ws;
    ushort* gbf = (ushort*)ws;   ws += SZ_TAB;                   // conv output (bf16)
    ushort* Gbf = (ushort*)ws;   ws += SZ_TAB;                   // gbf @ W1 (bf16)
    ushort* ebf = (ushort*)ws;   ws += SZ_TAB;                   // bf16 emb table
    ushort* w1t = (ushort*)ws;   ws += (size_t)DD * DD * sizeof(ushort);
    float* t2    = (float*)ws;   ws += (size_t)BB * DD * sizeof(float);
    float* alpha = (float*)ws;   ws += ((size_t)BB + 32) * sizeof(float);
    float* out   = (float*)d_out;

    k_emb_bf16<<<NN * DD / (256 * 4), 256, 0, stream>>>(item_emb, ebf);
    k_conv_all_bf16<<<NN / 4, 256, 0, stream>>>(ebf, adj_cols, adj_vals, gbf);
    k_prep_w1<<<DD / 4, 256, 0, stream>>>(at_w1, w1t);
    k_tprep<<<BB / 4, 256, 0, stream>>>(tgt, wf_w, wf_b, at_w2, at_bias,
                                        alphaw_w, alphaw_b, t2, alpha);
    k_gw1<<<NN / 64, 256, 0, stream>>>(gbf, w1t, Gbf);
    k_fused_entmax<<<BB, 256, 0, stream>>>(items, Gbf, gbf, t2, alpha, at_w0, out);
}